// Round 1
// 152.194 us; speedup vs baseline: 1.0173x; 1.0173x over previous
//
#include <hip/hip_runtime.h>

#define BLOCK 256

// Branch-free BCE matching jnp: -(t*clip(log p,-100) + (1-t)*clip(log1p(-p),-100))
// log1p(-p) -> __logf(1-p): abs err ~6e-8, far inside the 2e3 threshold.
__device__ __forceinline__ float bce_elem(float p, float t) {
    float lp  = fmaxf(__logf(p), -100.0f);        // v_log_f32(0) = -inf -> clamped
    float l1p = fmaxf(__logf(1.0f - p), -100.0f);
    return -__builtin_fmaf(t, lp - l1p, l1p);     // -(t*(lp-l1p) + l1p)
}

// Wave-cooperative lower_bound: first i in [0,n) with a[i] >= v (a ascending).
// 65-ary search: 64 lanes sample stratified points, ballot narrows the range.
// Depth for n=8M: 4 rounds of dependent loads vs 23 for scalar binary search.
__device__ __forceinline__ int wave_lower_bound(const int* __restrict__ a, int n, int v) {
    const int lane = threadIdx.x & 63;
    int lo = 0, hi = n;                       // answer L in [lo, hi]
    while (hi - lo > 64) {
        int range  = hi - lo;
        int stride = range / 65 + 1;
        int idx    = lo + (lane + 1) * stride;
        bool lt    = (idx < hi) && (a[idx] < v);   // prefix-shaped across lanes
        int  c     = __popcll(__ballot(lt));
        int  nlo   = lo + c * stride;              // a[nlo] < v (or nlo==lo)
        int  nhi   = nlo + stride;
        if (nhi > hi) nhi = hi;
        lo = nlo; hi = nhi;                        // range shrinks ~65x
    }
    int idx = lo + lane;
    bool ge = (idx >= hi) || (a[idx] >= v);
    unsigned long long bal = __ballot(ge);
    return bal ? (lo + __ffsll(bal) - 1) : hi;
}

// Per-element compute on one float4-triple.
#define PROC(p, t, m)                                                          \
    do {                                                                       \
        float m0 = (float)(m).x, m1 = (float)(m).y,                            \
              m2 = (float)(m).z, m3 = (float)(m).w;                            \
        accb += bce_elem((p).x * m0, (t).x);  accc += m0;                      \
        accb += bce_elem((p).y * m1, (t).y);  accc += m1;                      \
        accb += bce_elem((p).z * m2, (t).z);  accc += m2;                      \
        accb += bce_elem((p).w * m3, (t).w);  accc += m3;                      \
    } while (0)

// One block per segment (B=2048 -> exactly 8 blocks/CU at full occupancy).
// Hot loop: 3x-unrolled coalesced float4 stride loop -> 9 independent 16B
// loads in flight per thread (MLP fix for the latency-bound stream).
// __launch_bounds__(256,8) caps VGPRs at 64 so all 2048 blocks co-reside.
__global__ __launch_bounds__(BLOCK, 8) void seg_kernel(
    const float* __restrict__ pred, const float* __restrict__ tgt,
    const int* __restrict__ batch, const int* __restrict__ mask,
    const float* __restrict__ sat_pred, const float* __restrict__ sat_tgt,
    float* __restrict__ per_graph, int n, int Bseg)
{
    const int b   = blockIdx.x;
    const int tid = threadIdx.x;

    __shared__ int sh_bounds[2];
    const int wid = tid >> 6;
    if (wid < 2) {                            // wave 0 -> lo, wave 1 -> hi, concurrent
        int r = wave_lower_bound(batch, n, b + wid);
        if ((tid & 63) == 0) sh_bounds[wid] = r;
    }
    __syncthreads();
    const int lo = sh_bounds[0], hi = sh_bounds[1];   // block owns batch range [lo,hi)

    float accb = 0.0f, accc = 0.0f;

    int a0 = (lo + 3) & ~3;                   // first 16B-aligned element
    if (a0 > hi) a0 = hi;
    const int nvec = (hi - a0) >> 2;
    const int a1   = a0 + (nvec << 2);

    // scalar head (<=3 elems)
    for (int i = lo + tid; i < a0; i += BLOCK) {
        float mf = (float)mask[i];
        accb += bce_elem(pred[i] * mf, tgt[i]);
        accc += mf;
    }

    // vector body: 3 coalesced float4 streams, unrolled 3x.
    // All 9 loads are issued before any compute -> 144B in flight per thread.
    const float4* p4 = reinterpret_cast<const float4*>(pred) + (a0 >> 2);
    const float4* t4 = reinterpret_cast<const float4*>(tgt)  + (a0 >> 2);
    const int4*   m4 = reinterpret_cast<const int4*>(mask)   + (a0 >> 2);

    int i = tid;
    const int nv2 = nvec - 2 * BLOCK;
    for (; i < nv2; i += 3 * BLOCK) {
        float4 pa = p4[i], pb = p4[i + BLOCK], pc = p4[i + 2 * BLOCK];
        float4 ta = t4[i], tb = t4[i + BLOCK], tc = t4[i + 2 * BLOCK];
        int4   ma = m4[i], mb = m4[i + BLOCK], mc = m4[i + 2 * BLOCK];
        PROC(pa, ta, ma);
        PROC(pb, tb, mb);
        PROC(pc, tc, mc);
    }
    for (; i < nvec; i += BLOCK) {            // remainder (<=2 strided iters/thread)
        float4 p = p4[i];
        float4 t = t4[i];
        int4   m = m4[i];
        PROC(p, t, m);
    }

    // scalar tail (<=3 elems)
    for (int j = a1 + tid; j < hi; j += BLOCK) {
        float mf = (float)mask[j];
        accb += bce_elem(pred[j] * mf, tgt[j]);
        accc += mf;
    }

    // block reduction: wave shfl -> LDS -> thread 0
    #pragma unroll
    for (int o = 32; o > 0; o >>= 1) {
        accb += __shfl_xor(accb, o);
        accc += __shfl_xor(accc, o);
    }
    __shared__ float wb[4], wc[4];
    if ((tid & 63) == 0) { wb[tid >> 6] = accb; wc[tid >> 6] = accc; }
    __syncthreads();
    if (tid == 0) {
        float sb = wb[0] + wb[1] + wb[2] + wb[3];
        float sc = wc[0] + wc[1] + wc[2] + wc[3];
        float pg = (sc > 0.0f) ? sb / fmaxf(sc, 1.0f) : 0.0f;
        // fold this graph's share of the sat-BCE mean*L1 term; every b covered once
        pg += bce_elem(sat_pred[b], sat_tgt[b]) * ((1.0f / 50.0f) / (float)Bseg);
        per_graph[b] = pg;                    // plain store: no atomics anywhere
    }
}

__global__ __launch_bounds__(256) void sum_kernel(
    const float* __restrict__ per_graph, float* __restrict__ out, int Bseg)
{
    float local = 0.0f;
    for (int i = threadIdx.x; i < Bseg; i += 256) local += per_graph[i];
    #pragma unroll
    for (int o = 32; o > 0; o >>= 1) local += __shfl_xor(local, o);
    __shared__ float ws[4];
    if ((threadIdx.x & 63) == 0) ws[threadIdx.x >> 6] = local;
    __syncthreads();
    if (threadIdx.x == 0) out[0] = ws[0] + ws[1] + ws[2] + ws[3];
}

extern "C" void kernel_launch(void* const* d_in, const int* in_sizes, int n_in,
                              void* d_out, int out_size, void* d_ws, size_t ws_size,
                              hipStream_t stream) {
    const float* y_mus_pred = (const float*)d_in[0];
    const float* y_mus      = (const float*)d_in[1];
    const float* y_sat_pred = (const float*)d_in[2];
    const float* y_sat      = (const float*)d_in[3];
    const int*   batch      = (const int*)d_in[4];
    const int*   mask       = (const int*)d_in[5];

    const int n    = in_sizes[0];
    const int Bseg = in_sizes[2];

    float* per_graph = (float*)d_ws;   // Bseg floats; every slot written each launch

    seg_kernel<<<Bseg, BLOCK, 0, stream>>>(
        y_mus_pred, y_mus, batch, mask, y_sat_pred, y_sat, per_graph, n, Bseg);
    sum_kernel<<<1, 256, 0, stream>>>(per_graph, (float*)d_out, Bseg);
}